// Round 2
// baseline (95.674 us; speedup 1.0000x reference)
//
#include <hip/hip_runtime.h>

// Problem dims (fixed by reference)
#define Bb  8
#define Mm  4096
#define Nn  64
#define Ff  9
#define Ss  5
#define NRr 3

// Global atom-term table record per (b,n,j): 16 floats (4 x float4):
//  q0 = [bc = b*log2(e), p, 0, 0]
//  q1 = [A, ux, uy, uz]  for lm=0   (A = a*|c|, u = c/|c|)
//  q2 = ... lm=1
//  q3 = ... lm=2
constexpr int REC = 16;

__global__ void HarmonicGen_precompute(
    const float* __restrict__ coef,   // [B,N,F,3]
    const int*   __restrict__ labels, // [B,N]
    const float* __restrict__ pa,
    const float* __restrict__ pb,
    const float* __restrict__ pp,
    float*       __restrict__ table)  // [B*N*NR, 16]
{
    const int i = blockIdx.x * 256 + threadIdx.x;   // over B*N*NR = 1536
    if (i >= Bb * Nn * NRr) return;
    const int j  = i % NRr;
    const int bn = i / NRr;           // b*Nn + n
    const int s  = labels[bn];
    const float av = pa[s * NRr + j];
    const float bv = pb[s * NRr + j];
    const float pv = pp[s * NRr + j];
    float* rec = table + (size_t)i * REC;
    rec[0] = bv * 1.44269504088896340736f;  // b * log2(e)
    rec[1] = pv;
    rec[2] = 0.0f; rec[3] = 0.0f;
#pragma unroll
    for (int lm = 0; lm < 3; ++lm) {
        const int f = j * 3 + lm;
        const float* c = coef + ((size_t)bn * Ff + f) * 3;
        const float cx = c[0], cy = c[1], cz = c[2];
        const float cn  = sqrtf(cx * cx + cy * cy + cz * cz);
        const float inv = 1.0f / fmaxf(cn, 1e-12f);
        rec[4 + lm * 4 + 0] = av * cn;
        rec[4 + lm * 4 + 1] = cx * inv;
        rec[4 + lm * 4 + 2] = cy * inv;
        rec[4 + lm * 4 + 3] = cz * inv;
    }
}

constexpr int MT  = 64;    // m-tile per block (= lanes per wave)
constexpr int PAD = 193;   // 192 floats/row + 1 -> lane-stride 193 mod 32 = 1 (conflict-free)

__global__ __launch_bounds__(256, 2)
void HarmonicGenAMD_25786983645325_kernel(
    const float* __restrict__ dv,     // [B,M,N,3]
    const float* __restrict__ table,  // [B*N*NR, 16]
    float*       __restrict__ out)    // [B,M]
{
    __shared__ __align__(16) float dvs[MT * PAD];   // 49408 B
    __shared__ float red[4 * MT];                   // 1024 B

    const int tid = threadIdx.x;
    const int blk = blockIdx.x;       // 0..511
    const int b   = blk >> 6;
    const int m0  = (blk & 63) * MT;

    // ---- stage dv m-tile: 64 rows x 192 floats, fully coalesced float4 ----
    const float* g = dv + ((size_t)b * Mm + m0) * (Nn * 3);
    for (int i = tid * 4; i < MT * Nn * 3; i += 256 * 4) {
        const int row = i / 192;
        const int col = i - row * 192;
        const float4 v = *(const float4*)(g + (size_t)row * 192 + col);
        float* d = &dvs[row * PAD + col];
        d[0] = v.x; d[1] = v.y; d[2] = v.z; d[3] = v.w;
    }
    __syncthreads();

    // ---- main loop: lane = m_local (64 m per wave), wave = 16-atom slice ----
    // Atom index n = wid*16 + t is WAVE-UNIFORM -> table loads are uniform-address
    // (scalar-cache s_load path), zero LDS-pipe traffic for atom data.
    const int lane = tid & 63;
    const int wid  = tid >> 6;
    const float* drow = &dvs[lane * PAD];
    const float4* tb = (const float4*)(table + (size_t)b * Nn * NRr * REC);

    float acc = 0.0f;
#pragma unroll 4
    for (int t = 0; t < 16; ++t) {
        const int n = wid * 16 + t;
        const float x = drow[n * 3 + 0];
        const float y = drow[n * 3 + 1];
        const float z = drow[n * 3 + 2];
        const float r2   = x * x + y * y + z * z;
        const float r    = __builtin_amdgcn_sqrtf(r2);
        const float rinv = __builtin_amdgcn_rcpf(fmaxf(r, 1e-12f));
        const float l2r  = 0.5f * __builtin_amdgcn_logf(r2);   // log2(r)

        const float4* rec = tb + (size_t)n * (NRr * 4);
#pragma unroll
        for (int j = 0; j < NRr; ++j) {
            const float4 h = rec[j * 4 + 0];       // bc, p
            const float ek = __builtin_amdgcn_exp2f(__fmaf_rn(h.y, l2r, -h.x * r));
#pragma unroll
            for (int lm = 0; lm < 3; ++lm) {
                const float4 e = rec[j * 4 + 1 + lm];            // A, ux, uy, uz
                const float kern = e.x * ek;
                const float cosv = (x * e.y + y * e.z + z * e.w) * rinv;
                float q;
                if (lm == 0)      q = cosv;                                   // P1
                else if (lm == 1) q = __fmaf_rn(1.5f * cosv, cosv, -0.5f);    // P2
                else              q = cosv * __fmaf_rn(2.5f * cosv, cosv, -1.5f); // P3
                acc = __fmaf_rn(kern, q, acc);
            }
        }
    }

    // ---- cross-wave reduction (4 waves), coalesced store ----
    red[wid * MT + lane] = acc;
    __syncthreads();
    if (tid < MT) {
        const float s = red[tid] + red[MT + tid] + red[2 * MT + tid] + red[3 * MT + tid];
        out[(size_t)b * Mm + m0 + tid] = s;
    }
}

extern "C" void kernel_launch(void* const* d_in, const int* in_sizes, int n_in,
                              void* d_out, int out_size, void* d_ws, size_t ws_size,
                              hipStream_t stream) {
    const float* dv   = (const float*)d_in[0];
    const float* coef = (const float*)d_in[1];
    const int*   lab  = (const int*)d_in[2];
    const float* pa   = (const float*)d_in[3];
    const float* pb   = (const float*)d_in[4];
    const float* pp   = (const float*)d_in[5];
    float* out   = (float*)d_out;
    float* table = (float*)d_ws;   // 8*64*3*16*4 = 96 KiB, rebuilt every call (ws is re-poisoned)

    HarmonicGen_precompute<<<(Bb * Nn * NRr + 255) / 256, 256, 0, stream>>>(
        coef, lab, pa, pb, pp, table);

    dim3 grid(Bb * (Mm / MT));  // 512 blocks
    HarmonicGenAMD_25786983645325_kernel<<<grid, 256, 0, stream>>>(dv, table, out);
}

// Round 3
// 88.490 us; speedup vs baseline: 1.0812x; 1.0812x over previous
//
#include <hip/hip_runtime.h>

// Problem dims (fixed by reference)
#define Bb  8
#define Mm  4096
#define Nn  64
#define Ff  9
#define Ss  5
#define NRr 3

// Per-atom table record: 48 floats (192 B), per (b,n):
//  [0]=bc0 [1]=p0 [2]=bc1 [3]=p1 [4]=bc2 [5]=p2 [6,7]=pad   (bc = b*log2 e)
//  [8+f*4 .. 11+f*4] = A_f, ux, uy, uz    f = 0..8  (A = a*|c|, u = c/|c|)
constexpr int REC = 48;

__global__ void HarmonicGen_precompute(
    const float* __restrict__ coef,   // [B,N,F,3]
    const int*   __restrict__ labels, // [B,N]
    const float* __restrict__ pa,
    const float* __restrict__ pb,
    const float* __restrict__ pp,
    float*       __restrict__ table)  // [B*N, 48]
{
    const int i = blockIdx.x * 256 + threadIdx.x;   // over B*N = 512
    if (i >= Bb * Nn) return;
    const int s = labels[i];
    float* rec = table + (size_t)i * REC;
#pragma unroll
    for (int j = 0; j < NRr; ++j) {
        rec[j * 2 + 0] = pb[s * NRr + j] * 1.44269504088896340736f;
        rec[j * 2 + 1] = pp[s * NRr + j];
    }
    rec[6] = 0.0f; rec[7] = 0.0f;
#pragma unroll
    for (int f = 0; f < Ff; ++f) {
        const int j = f / 3;
        const float* c = coef + ((size_t)i * Ff + f) * 3;
        const float cx = c[0], cy = c[1], cz = c[2];
        const float cn  = sqrtf(cx * cx + cy * cy + cz * cz);
        const float inv = 1.0f / fmaxf(cn, 1e-12f);
        rec[8 + f * 4 + 0] = pa[s * NRr + j] * cn;
        rec[8 + f * 4 + 1] = cx * inv;
        rec[8 + f * 4 + 2] = cy * inv;
        rec[8 + f * 4 + 3] = cz * inv;
    }
}

constexpr int MT  = 64;    // m per block (= lane)
constexpr int PAD = 193;   // 192+1 floats/row -> (lane*193+3n+c)%32 hits all banks 2-way (free)

__global__ __launch_bounds__(256)
void HarmonicGenAMD_25786983645325_kernel(
    const float* __restrict__ dv,     // [B,M,N,3]
    const float* __restrict__ table,  // [B*N, 48]
    float*       __restrict__ out)    // [B,M]
{
    __shared__ __align__(16) float dvs[MT * PAD];   // 49408 B
    __shared__ float red[256];

    const int tid = threadIdx.x;
    const int blk = blockIdx.x;       // 0..511
    const int b   = blk >> 6;
    const int m0  = (blk & 63) * MT;

    // ---- stage dv m-tile: 64 rows x 192 floats, coalesced float4 global loads ----
    const float* g = dv + ((size_t)b * Mm + m0) * (Nn * 3);
    for (int i = tid * 4; i < MT * Nn * 3; i += 256 * 4) {
        const int row = i / 192;
        const int col = i - row * 192;
        const float4 v = *(const float4*)(g + (size_t)row * 192 + col);
        float* d = &dvs[row * PAD + col];   // odd stride: 4x ds_write_b32 (conflict-free)
        d[0] = v.x; d[1] = v.y; d[2] = v.z; d[3] = v.w;
    }
    __syncthreads();

    // ---- main loop: lane = m_local, wave = 16-atom slice ----
    // readfirstlane forces the atom base into an SGPR -> table addresses are
    // PROVABLY uniform -> s_load_dwordx4/x8 via scalar cache (no VMEM, no LDS).
    const int lane  = tid & 63;
    const int nbase = __builtin_amdgcn_readfirstlane((tid >> 6) * 16);
    const float* tb   = table + ((size_t)b * Nn + nbase) * REC;
    const float* drow = &dvs[lane * PAD + nbase * 3];

    float acc = 0.0f;
#pragma unroll 4
    for (int t = 0; t < 16; ++t) {
        const float* rec = tb + t * REC;        // uniform (SGPR base + const)
        const float x = drow[t * 3 + 0];
        const float y = drow[t * 3 + 1];
        const float z = drow[t * 3 + 2];
        const float r2   = __fmaf_rn(x, x, __fmaf_rn(y, y, z * z));
        const float rinv = __builtin_amdgcn_rsqf(r2);          // 1/r
        const float r    = r2 * rinv;
        const float l2r  = 0.5f * __builtin_amdgcn_logf(r2);   // log2(r)
        const float dnx = x * rinv, dny = y * rinv, dnz = z * rinv;

        const float4 h0 = *(const float4*)(rec);       // bc0,p0,bc1,p1
        const float2 h1 = *(const float2*)(rec + 4);   // bc2,p2
        float ek[3];
        ek[0] = __builtin_amdgcn_exp2f(__fmaf_rn(h0.y, l2r, -h0.x * r));
        ek[1] = __builtin_amdgcn_exp2f(__fmaf_rn(h0.w, l2r, -h0.z * r));
        ek[2] = __builtin_amdgcn_exp2f(__fmaf_rn(h1.y, l2r, -h1.x * r));
#pragma unroll
        for (int f = 0; f < Ff; ++f) {
            const float4 e = *(const float4*)(rec + 8 + f * 4);  // A, ux, uy, uz
            const float c = __fmaf_rn(dnx, e.y, __fmaf_rn(dny, e.z, dnz * e.w));
            float q;
            if      (f % 3 == 0) q = c;                                    // P1
            else if (f % 3 == 1) q = __fmaf_rn(1.5f * c, c, -0.5f);        // P2
            else                 q = c * __fmaf_rn(2.5f * c, c, -1.5f);    // P3
            acc = __fmaf_rn(e.x * ek[f / 3], q, acc);
        }
    }

    // ---- cross-wave reduction (4 waves), coalesced store ----
    red[tid] = acc;
    __syncthreads();
    if (tid < MT) {
        out[(size_t)b * Mm + m0 + tid] =
            red[tid] + red[MT + tid] + red[2 * MT + tid] + red[3 * MT + tid];
    }
}

extern "C" void kernel_launch(void* const* d_in, const int* in_sizes, int n_in,
                              void* d_out, int out_size, void* d_ws, size_t ws_size,
                              hipStream_t stream) {
    const float* dv   = (const float*)d_in[0];
    const float* coef = (const float*)d_in[1];
    const int*   lab  = (const int*)d_in[2];
    const float* pa   = (const float*)d_in[3];
    const float* pb   = (const float*)d_in[4];
    const float* pp   = (const float*)d_in[5];
    float* out   = (float*)d_out;
    float* table = (float*)d_ws;   // 512*48*4 = 96 KiB, rebuilt every call

    HarmonicGen_precompute<<<2, 256, 0, stream>>>(coef, lab, pa, pb, pp, table);

    dim3 grid(Bb * (Mm / MT));  // 512 blocks
    HarmonicGenAMD_25786983645325_kernel<<<grid, 256, 0, stream>>>(dv, table, out);
}